// Round 13
// baseline (478.937 us; speedup 1.0000x reference)
//
#include <hip/hip_runtime.h>
#include <hip/hip_bf16.h>
#include <math.h>

#define W_    320
#define H_    256
#define HW_   81920      // H_*W_
#define BHW_  327680     // 4*HW_
#define PRM_TOT 49786
#define WCH   86         // wbuf channels/batch: 83 gen-kernel + 3 ct-logit
#define PW_   326        // padded field width  (W + 2*3)
#define PH_   262        // padded field height (H + 2*3)
#define PHW_  85412      // PW_*PH_

// prm layout offsets (floats)
#define OW3  0
#define OW5  4608
#define OW7  18432
#define OCK  46080
#define OCT  47808
#define OG3  49617
#define OB3  49625
#define OG5  49633
#define OB5  49657
#define OG7  49681
#define OB7  49729
#define OCKB 49777
#define OCTB 49780
#define OSIG 49783

typedef unsigned short u16;
typedef __attribute__((ext_vector_type(8))) short short8;   // 8 bf16 (4 VGPRs)
typedef __attribute__((ext_vector_type(4))) float f32x4;    // MFMA C/D

__device__ __forceinline__ float dload(const void* p, size_t i, int isbf) {
  return isbf ? __bfloat162float(((const __hip_bfloat16*)p)[i])
              : ((const float*)p)[i];
}

__device__ __forceinline__ u16 f32_bf16_rne(float f) {
  union { float f; unsigned u; } v; v.f = f;
  unsigned r = v.u + 0x7FFFu + ((v.u >> 16) & 1u);
  return (u16)(r >> 16);
}
__device__ __forceinline__ float bf16_f32(u16 h) {
  union { unsigned u; float f; } v; v.u = ((unsigned)h) << 16;
  return v.f;
}

// Weight quantization: weights provably in [0,1]; u16 fixed point, 2^-16.
__device__ __forceinline__ unsigned wquant(float w) {
  int v = (int)(w * 65536.f + 0.5f);
  return (unsigned)(v > 65535 ? 65535 : (v < 0 ? 0 : v));
}

// ---------------------------------------------------------------------------
// Per-tensor dtype detector (kept for robustness; observed: all f32).
// ---------------------------------------------------------------------------
__global__ __launch_bounds__(512) void k_detect(
    const void* t0, const void* t1, const void* t2, const void* t3,
    const void* t4, const void* t5, const void* t6, const void* t7,
    const void* t8, const void* t9, const void* t10, const void* t11,
    const void* t12, const void* t13, const void* t14, const void* t15,
    const void* t16, const void* t17, int* __restrict__ flags)
{
  __shared__ int c_other, c_zeven, c_zodd, c_m;
  const void* ptrs[18] = {t0,t1,t2,t3,t4,t5,t6,t7,t8,t9,
                          t10,t11,t12,t13,t14,t15,t16,t17};
  const int ns[18] = {20971520, 327680, 4608, 8, 8, 13824, 24, 24,
                      27648, 48, 48, 1728, 3, 1809, 3, 1, 1, 1};
  const int tensor = blockIdx.x;
  const int n = ns[tensor];
  const unsigned short* u = (const unsigned short*)ptrs[tensor];
  if (threadIdx.x == 0) { c_other = 0; c_zeven = 0; c_zodd = 0; c_m = 0; }
  __syncthreads();
  {
    int k = threadIdx.x >> 1;
    long long pos = (long long)k * n / 256;
    int j = ((int)pos & ~1) + (threadIdx.x & 1);
    if (j < n) {
      unsigned short v = u[j];
      int e = (v >> 7) & 0xFF;
      atomicAdd(&c_m, 1);
      if (v != 0 && (e < 90 || e > 150)) atomicAdd(&c_other, 1);
      if (v == 0) {
        if (j & 1) atomicAdd(&c_zodd, 1); else atomicAdd(&c_zeven, 1);
      }
    }
  }
  __syncthreads();
  if (threadIdx.x == 0) {
    int isf32;
    if (n == 1) isf32 = (u[0] == 0);
    else        isf32 = (4 * c_other >= c_m) ||
                        (2 * (c_zeven - c_zodd) >= c_m);
    flags[tensor] = isf32 ? 0 : 1;
  }
}

// ---------------------------------------------------------------------------
// K0: convert params to f32 staging `prm` (per-tensor dtype).
// ---------------------------------------------------------------------------
__global__ __launch_bounds__(256) void k_cvt(
    const void* w3c, const void* w5c, const void* w7c, const void* ckw, const void* ctw,
    const void* g3, const void* b3, const void* g5, const void* b5,
    const void* g7, const void* b7, const void* ckb, const void* ctb,
    const void* s3, const void* s5, const void* s7,
    float* __restrict__ prm, const int* __restrict__ flags)
{
  int j = blockIdx.x * 256 + threadIdx.x;
  if (j >= PRM_TOT) return;
  const void* src; int off; int fid;
  if      (j < OW5)    { src = w3c; off = OW3;  fid = 2; }
  else if (j < OW7)    { src = w5c; off = OW5;  fid = 5; }
  else if (j < OCK)    { src = w7c; off = OW7;  fid = 8; }
  else if (j < OCT)    { src = ckw; off = OCK;  fid = 11; }
  else if (j < OG3)    { src = ctw; off = OCT;  fid = 13; }
  else if (j < OB3)    { src = g3;  off = OG3;  fid = 3; }
  else if (j < OG5)    { src = b3;  off = OB3;  fid = 4; }
  else if (j < OB5)    { src = g5;  off = OG5;  fid = 6; }
  else if (j < OG7)    { src = b5;  off = OB5;  fid = 7; }
  else if (j < OB7)    { src = g7;  off = OG7;  fid = 9; }
  else if (j < OCKB)   { src = b7;  off = OB7;  fid = 10; }
  else if (j < OCTB)   { src = ckb; off = OCKB; fid = 12; }
  else if (j < OSIG)   { src = ctb; off = OCTB; fid = 14; }
  else if (j < OSIG+1) { src = s3;  off = OSIG;   fid = 15; }
  else if (j < OSIG+2) { src = s5;  off = OSIG+1; fid = 16; }
  else                 { src = s7;  off = OSIG+2; fid = 17; }
  prm[j] = dload(src, j - off, flags[fid]);
}

// ---------------------------------------------------------------------------
// K0c: stage hn into a padded f32 field (3-px zero halo, dtype-converted).
// ---------------------------------------------------------------------------
__global__ __launch_bounds__(256) void k_padhn(
    const void* __restrict__ rawhn, float* __restrict__ hnp,
    const int* __restrict__ flags)
{
  const int isbf = flags[1];
  const int p = blockIdx.x * 256 + threadIdx.x;
  const int b = p / HW_, q = p - b * HW_;
  const int y = q / W_, x = q - y * W_;
  hnp[(size_t)b * PHW_ + (size_t)(y + 3) * PW_ + (x + 3)] =
      dload(rawhn, (size_t)b * HW_ + q, isbf);
}

// ---------------------------------------------------------------------------
// K0b: pack conv weights into MFMA A-fragment order, split bf16 hi/lo.
// ---------------------------------------------------------------------------
__global__ __launch_bounds__(256) void k_pack(
    const float* __restrict__ prm, u16* __restrict__ apack)
{
  int idx = blockIdx.x * 256 + threadIdx.x;   // grid exactly 110592
  int e = idx & 7;
  int lane = (idx >> 3) & 63;
  int t = idx >> 9;
  int mt = t % 6; t /= 6;
  int chunk = t & 1; t >>= 1;
  int tap = t % 9;
  int hilo = t / 9;
  int oc = mt * 16 + (lane & 15);
  int ic = chunk * 32 + (lane >> 4) * 8 + e;
  float w = 0.f;
  if (oc < 83)      w = prm[(size_t)oc * 576 + (size_t)ic * 9 + tap];
  else if (oc < 86) w = prm[OCT + (size_t)((oc - 83) * 67 + ic) * 9 + tap];
  u16 h = f32_bf16_rne(w);
  u16 outv = (hilo == 0) ? h : f32_bf16_rne(w - bf16_f32(h));
  apack[idx] = outv;
}

// ---------------------------------------------------------------------------
// Staging: fout tile [6 rows][66 px][32 ic-chunk] -> LDS bf16 hi + lo.
// ---------------------------------------------------------------------------
template<int ISBF>
__device__ __forceinline__ void stage_chunk(
    const void* __restrict__ fout, int b, int y0, int x0, int chunk,
    u16* Bhi, u16* Blo)
{
  const int g = threadIdx.x & 3;        // ic8 group within chunk
  const int cell0 = threadIdx.x >> 2;   // (row,px) cell, 0..63
  const size_t fb = (size_t)b * 64 * HW_ + (size_t)(chunk * 32 + g * 8) * HW_;
#pragma unroll
  for (int it = 0; it < 7; ++it) {
    int cell = cell0 + it * 64;
    if (cell < 396) {
      int row = cell / 66;
      int px = cell - row * 66;
      int gy = y0 - 1 + row, gx = x0 - 1 + px;
      bool ok = ((unsigned)gy < H_) && ((unsigned)gx < W_);
      size_t base = fb + (size_t)gy * W_ + gx;
      short8 hs = {0,0,0,0,0,0,0,0};
      short8 ls = {0,0,0,0,0,0,0,0};
#pragma unroll
      for (int i = 0; i < 8; ++i) {
        float v = ok ? dload(fout, base + (size_t)i * HW_, ISBF) : 0.f;
        union { float f; unsigned u; } uv; uv.f = v;
        u16 h = (u16)(uv.u >> 16);               // truncate: hi
        float resid = v - bf16_f32(h);           // exact residual
        hs[i] = (short)h;
        ls[i] = (short)f32_bf16_rne(resid);
      }
      int off = ((row * 66 + px) * 32 + g * 8) * 2;
      off ^= (px & 7) << 4;
      *(short8*)((char*)Bhi + off) = hs;
      *(short8*)((char*)Blo + off) = ls;
    }
  }
}

// ---------------------------------------------------------------------------
// K1: 3x3 conv 64->86 as implicit GEMM on MFMA (split-bf16, 3-term).
// FROZEN (round-11 verified clean): 256 thr = 4 waves, 6 mtiles/wave,
// (256,2) = 256-reg budget (128 arch + 96 acc fits), C-store-only epilogue.
// ---------------------------------------------------------------------------
__global__ __launch_bounds__(256, 2) void k_conv_mfma(
    const void* __restrict__ fout, const u16* __restrict__ apack,
    float* __restrict__ wbuf, const int* __restrict__ flags)
{
  __shared__ __align__(16) u16 Bhi[6 * 66 * 32];
  __shared__ __align__(16) u16 Blo[6 * 66 * 32];
  const int isbf = flags[0];
  const int x0 = blockIdx.x * 64;
  const int y0 = blockIdx.y * 4;
  const int b  = blockIdx.z;
  const int lane = threadIdx.x & 63;
  const int wv   = threadIdx.x >> 6;    // 0..3 = row within tile

  const f32x4 zero = {0.f, 0.f, 0.f, 0.f};
  f32x4 acc[6][4];
#pragma unroll
  for (int mt = 0; mt < 6; ++mt)
#pragma unroll
    for (int nt = 0; nt < 4; ++nt)
      acc[mt][nt] = zero;

  for (int chunk = 0; chunk < 2; ++chunk) {
    if (chunk) __syncthreads();
    if (isbf) stage_chunk<1>(fout, b, y0, x0, chunk, Bhi, Blo);
    else      stage_chunk<0>(fout, b, y0, x0, chunk, Bhi, Blo);
    __syncthreads();

#pragma unroll
    for (int tap = 0; tap < 9; ++tap) {
      const int dy = tap / 3, dx = tap - dy * 3;
      const int row = wv + dy;
      short8 bh[4], bl[4];
#pragma unroll
      for (int nt = 0; nt < 4; ++nt) {
        int px = nt * 16 + (lane & 15) + dx;
        int off = ((row * 66 + px) * 32 + (lane >> 4) * 8) * 2;
        off ^= (px & 7) << 4;
        bh[nt] = *(const short8*)((const char*)Bhi + off);
        bl[nt] = *(const short8*)((const char*)Blo + off);
      }
      const u16* abase = apack + (size_t)(tap * 2 + chunk) * 3072 + (size_t)lane * 8;
#pragma unroll
      for (int mt = 0; mt < 6; ++mt) {
        short8 ah = *(const short8*)(abase + (size_t)mt * 512);
        short8 al = *(const short8*)(abase + (size_t)mt * 512 + 55296);
#pragma unroll
        for (int nt = 0; nt < 4; ++nt) {
          acc[mt][nt] = __builtin_amdgcn_mfma_f32_16x16x32_bf16(ah, bh[nt], acc[mt][nt], 0, 0, 0);
          acc[mt][nt] = __builtin_amdgcn_mfma_f32_16x16x32_bf16(ah, bl[nt], acc[mt][nt], 0, 0, 0);
          acc[mt][nt] = __builtin_amdgcn_mfma_f32_16x16x32_bf16(al, bh[nt], acc[mt][nt], 0, 0, 0);
        }
      }
    }
  }

  // Epilogue: C/D layout col=lane&15 (px), row=(lane>>4)*4+reg (oc). [m89]
  const int ocr = (lane >> 4) * 4;
  float* wb = wbuf + (size_t)b * WCH * HW_
            + (size_t)(y0 + wv) * W_ + x0 + (lane & 15);
#pragma unroll
  for (int mt = 0; mt < 6; ++mt) {
#pragma unroll
    for (int nt = 0; nt < 4; ++nt) {
#pragma unroll
      for (int r = 0; r < 4; ++r) {
        int oc = mt * 16 + ocr + r;
        if (oc < 86)
          wb[(size_t)oc * HW_ + nt * 16] = acc[mt][nt][r];
      }
    }
  }
}

// ---------------------------------------------------------------------------
// K1s: BN statistics over wbuf channels 0..79 (WCH stride), float4 loads.
// ---------------------------------------------------------------------------
__global__ __launch_bounds__(256) void k_stats(
    const float* __restrict__ wbuf, float* __restrict__ stat)
{
  const int ch = blockIdx.y;
  const int HW4 = HW_ / 4;
  float s = 0.f, qq = 0.f;
  for (int idx = blockIdx.x * 256 + threadIdx.x; idx < BHW_ / 4;
       idx += gridDim.x * 256) {
    int b = idx / HW4, r = idx - b * HW4;
    float4 v = *(const float4*)(wbuf + ((size_t)(b * WCH + ch)) * HW_ +
                                (size_t)r * 4);
    s  += v.x + v.y + v.z + v.w;
    qq += v.x * v.x + v.y * v.y + v.z * v.z + v.w * v.w;
  }
#pragma unroll
  for (int m = 1; m < 64; m <<= 1) {
    s += __shfl_xor(s, m, 64);
    qq += __shfl_xor(qq, m, 64);
  }
  __shared__ float rs[4], rq[4];
  const int lane = threadIdx.x & 63, wv = threadIdx.x >> 6;
  if (lane == 0) { rs[wv] = s; rq[wv] = qq; }
  __syncthreads();
  if (threadIdx.x == 0) {
    float ts = rs[0] + rs[1] + rs[2] + rs[3];
    float tq = rq[0] + rq[1] + rq[2] + rq[3];
    atomicAdd(&stat[ch], ts);
    atomicAdd(&stat[80 + ch], tq);
  }
}

// ---------------------------------------------------------------------------
// K1b: finalize BN mean / invstd
// ---------------------------------------------------------------------------
__global__ void k_bn_finalize(float* __restrict__ stat)
{
  int ch = threadIdx.x;
  if (ch < 80) {
    const float n = 1.f / (float)BHW_;
    float m = stat[ch] * n;
    float var = stat[80 + ch] * n - m * m;
    stat[160 + ch] = m;
    stat[240 + ch] = rsqrtf(var + 1e-5f);
  }
}

// ---------------------------------------------------------------------------
// K2: fused weight-gen + prop iteration 0 (unchanged from round 12):
// writes u16 pairs channel-major to wbuf ch 0..41 (own-pixel, race-free).
// ---------------------------------------------------------------------------
__global__ __launch_bounds__(256, 2) void k_prop0(
    float* __restrict__ wbuf, float* __restrict__ conf,
    const float* __restrict__ hnp,
    float* __restrict__ h3o, float* __restrict__ h5o, float* __restrict__ h7o,
    const float* __restrict__ prm, const float* __restrict__ stat)
{
  const int p = blockIdx.x * 256 + threadIdx.x;
  const int b = p / HW_, q = p - b * HW_;
  const int y = q / W_, x = q - y * W_;
  float* base = wbuf + ((size_t)b * WCH) * HW_ + q;
  const float* mean = stat + 160;
  const float* istd = stat + 240;
  const size_t pc = (size_t)b * PHW_ + (size_t)(y + 3) * PW_ + (x + 3);
  const float* hc = hnp + pc;

  // ---- conf softmax (raw ck channels 80..82) ----
  {
    float c0 = base[(size_t)80 * HW_] + prm[OCKB + 0];
    float c1 = base[(size_t)81 * HW_] + prm[OCKB + 1];
    float c2 = base[(size_t)82 * HW_] + prm[OCKB + 2];
    float m = fmaxf(c0, fmaxf(c1, c2));
    float e0 = expf(c0 - m), e1 = expf(c1 - m), e2 = expf(c2 - m);
    float inv = 1.f / (e0 + e1 + e2);
    float* cf = conf + ((size_t)b * 3) * HW_ + q;
    cf[0] = e0 * inv;
    cf[(size_t)HW_] = e1 * inv;
    cf[(size_t)2 * HW_] = e2 * inv;
  }

  float a3, a5, a7;
  unsigned carry;   // low half of pair 4 (kernel channel 8)

  // ---- pk=3 ----
  {
    float cvv[8]; float s = 0.f;
#pragma unroll
    for (int i = 0; i < 8; ++i) {
      float v = base[(size_t)i * HW_];
      v = fmaxf(0.f, (v - mean[i]) * istd[i] * prm[OG3 + i] + prm[OB3 + i]);
      cvv[i] = v; s += v;
    }
    float inv = 1.f / (s + 1e-6f);
    float ctr = 1.f - s * inv;
    float sg = prm[OSIG + 0];
    float a = 0.5f / (sg * sg);
    float e1 = expf(-a);
    float g1[3] = {e1, 1.f, e1};
    float tot = 0.f;
#pragma unroll
    for (int j = 0; j < 9; ++j) {
      float w = (j == 4) ? ctr : cvv[j < 4 ? j : j - 1] * inv;
      w *= g1[j / 3] * g1[j % 3];
      if (j == 4) ctr = w; else cvv[j < 4 ? j : j - 1] = w;
      tot += w;
    }
    float rr = 1.f / fmaxf(tot, 1e-7f);
    auto wk = [&](int c) -> float {
      return ((c == 4) ? ctr : cvv[c < 4 ? c : c - 1]) * rr;
    };
    a3 = 0.f;
#pragma unroll
    for (int j = 0; j < 9; ++j)
      a3 = fmaf(wk(j), hc[(j / 3 - 1) * PW_ + (j % 3 - 1)], a3);
#pragma unroll
    for (int pr = 0; pr < 4; ++pr)
      base[(size_t)pr * HW_] =
          __uint_as_float(wquant(wk(2 * pr)) | (wquant(wk(2 * pr + 1)) << 16));
    carry = wquant(wk(8));
  }

  // ---- pk=5 ----
  {
    float cvv[24]; float s = 0.f;
#pragma unroll
    for (int i = 0; i < 24; ++i) {
      float v = base[(size_t)(8 + i) * HW_];
      v = fmaxf(0.f, (v - mean[8 + i]) * istd[8 + i] * prm[OG5 + i] + prm[OB5 + i]);
      cvv[i] = v; s += v;
    }
    float inv = 1.f / (s + 1e-6f);
    float ctr = 1.f - s * inv;
    float sg = prm[OSIG + 1];
    float a = 0.5f / (sg * sg);
    float ea = expf(-a), eb = expf(-0.25f * a);
    float g1[5] = {ea, eb, 1.f, eb, ea};
    float tot = 0.f;
#pragma unroll
    for (int j = 0; j < 25; ++j) {
      float w = (j == 12) ? ctr : cvv[j < 12 ? j : j - 1] * inv;
      w *= g1[j / 5] * g1[j % 5];
      if (j == 12) ctr = w; else cvv[j < 12 ? j : j - 1] = w;
      tot += w;
    }
    float rr = 1.f / fmaxf(tot, 1e-7f);
    auto wk = [&](int j) -> float {
      return ((j == 12) ? ctr : cvv[j < 12 ? j : j - 1]) * rr;
    };
    a5 = 0.f;
#pragma unroll
    for (int j = 0; j < 25; ++j)
      a5 = fmaf(wk(j), hc[(j / 5 - 2) * PW_ + (j % 5 - 2)], a5);
    base[(size_t)4 * HW_] = __uint_as_float(carry | (wquant(wk(0)) << 16));
#pragma unroll
    for (int m = 0; m < 12; ++m)
      base[(size_t)(5 + m) * HW_] =
          __uint_as_float(wquant(wk(1 + 2 * m)) | (wquant(wk(2 + 2 * m)) << 16));
  }

  // ---- pk=7 ----
  {
    float cvv[48]; float s = 0.f;
#pragma unroll
    for (int i = 0; i < 48; ++i) {
      float v = base[(size_t)(32 + i) * HW_];
      v = fmaxf(0.f, (v - mean[32 + i]) * istd[32 + i] * prm[OG7 + i] + prm[OB7 + i]);
      cvv[i] = v; s += v;
    }
    float inv = 1.f / (s + 1e-6f);
    float ctr = 1.f - s * inv;
    float sg = prm[OSIG + 2];
    float a = 0.5f / (sg * sg);
    float ea = expf(-a), eb = expf(-(4.f / 9.f) * a), ec = expf(-(1.f / 9.f) * a);
    float g1[7] = {ea, eb, ec, 1.f, ec, eb, ea};
    float tot = 0.f;
#pragma unroll
    for (int j = 0; j < 49; ++j) {
      float w = (j == 24) ? ctr : cvv[j < 24 ? j : j - 1] * inv;
      w *= g1[j / 7] * g1[j % 7];
      if (j == 24) ctr = w; else cvv[j < 24 ? j : j - 1] = w;
      tot += w;
    }
    float rr = 1.f / fmaxf(tot, 1e-7f);
    auto wk = [&](int j) -> float {
      return ((j == 24) ? ctr : cvv[j < 24 ? j : j - 1]) * rr;
    };
    a7 = 0.f;
#pragma unroll
    for (int j = 0; j < 49; ++j)
      a7 = fmaf(wk(j), hc[(j / 7 - 3) * PW_ + (j % 7 - 3)], a7);
#pragma unroll
    for (int m = 0; m < 24; ++m)
      base[(size_t)(17 + m) * HW_] =
          __uint_as_float(wquant(wk(2 * m)) | (wquant(wk(2 * m + 1)) << 16));
    base[(size_t)41 * HW_] = __uint_as_float(wquant(wk(48)));
  }

  h3o[pc] = a3;
  h5o[pc] = a5;
  h7o[pc] = a7;
}

// ---------------------------------------------------------------------------
// K2b: transpose quantized weights to pixel-major for vectorized prop reads.
// Reads ch 0..41 (own pixel); writes: pairs 0..39 as 40-dword records into
// dead ch 43..82 (record q at q*40 dwords, 160 B, 16B-aligned); pair 40 to
// ch 42 (own pixel); pair 41 to xw. Read/write channel sets are disjoint ->
// race-free. Runs after k_prop0 (ch 42..82 dead by then).
// ---------------------------------------------------------------------------
__global__ __launch_bounds__(256) void k_wt(
    float* __restrict__ wbuf, float* __restrict__ xw)
{
  const int p = blockIdx.x * 256 + threadIdx.x;
  const int b = p / HW_, q = p - b * HW_;
  float* base = wbuf + (size_t)b * WCH * HW_;
  float v[42];
#pragma unroll
  for (int c = 0; c < 42; ++c) v[c] = base[(size_t)c * HW_ + q];
  float4* dst = (float4*)(base + (size_t)43 * HW_ + (size_t)q * 40);
#pragma unroll
  for (int i = 0; i < 10; ++i) {
    float4 t;
    t.x = v[4 * i]; t.y = v[4 * i + 1]; t.z = v[4 * i + 2]; t.w = v[4 * i + 3];
    dst[i] = t;
  }
  base[(size_t)42 * HW_ + q] = v[40];
  xw[(size_t)b * HW_ + q] = v[41];
}

// ---------------------------------------------------------------------------
// K3: propagation iterations 1..5, padded fields, pixel-major weights:
// 10 x dwordx4 + 2 dwords instead of 42 scalar strided loads. Decode order
// identical to round 12 (bit-identical results).
// ---------------------------------------------------------------------------
__global__ __launch_bounds__(256) void k_prop_q(
    const float* __restrict__ wq,    // wbuf base (records at ch43; pair40 at ch42)
    const float* __restrict__ xw,    // pair 41, batch stride HW_
    const float* __restrict__ conf,
    const float* __restrict__ in3, const float* __restrict__ in5,
    const float* __restrict__ in7, size_t bsi,
    float* __restrict__ out3, float* __restrict__ out5,
    float* __restrict__ out7, size_t bso,
    float* __restrict__ combo, int store_h)
{
  const int p = blockIdx.x * 256 + threadIdx.x;
  const int b = p / HW_, q = p - b * HW_;
  const int y = q / W_, x = q - y * W_;
  const float* base = wq + (size_t)b * WCH * HW_;

  unsigned pk[42];
  const float4* wr = (const float4*)(base + (size_t)43 * HW_ + (size_t)q * 40);
#pragma unroll
  for (int i = 0; i < 10; ++i) {
    float4 v = wr[i];
    pk[4 * i + 0] = __float_as_uint(v.x);
    pk[4 * i + 1] = __float_as_uint(v.y);
    pk[4 * i + 2] = __float_as_uint(v.z);
    pk[4 * i + 3] = __float_as_uint(v.w);
  }
  pk[40] = __float_as_uint(base[(size_t)42 * HW_ + q]);
  pk[41] = __float_as_uint(xw[(size_t)b * HW_ + q]);
#define WRAW(CH) ((float)((pk[(CH) >> 1] >> (((CH) & 1) * 16)) & 0xffffu))

  const size_t pc = (size_t)(y + 3) * PW_ + (x + 3);
  const float* c3 = in3 + (size_t)b * bsi + pc;
  const float* c5 = in5 + (size_t)b * bsi + pc;
  const float* c7 = in7 + (size_t)b * bsi + pc;

  float a3 = 0.f, a5 = 0.f, a7 = 0.f;
#pragma unroll
  for (int j = 0; j < 9; ++j)
    a3 = fmaf(WRAW(j), c3[(j / 3 - 1) * PW_ + (j % 3 - 1)], a3);
#pragma unroll
  for (int j = 0; j < 25; ++j)
    a5 = fmaf(WRAW(9 + j), c5[(j / 5 - 2) * PW_ + (j % 5 - 2)], a5);
#pragma unroll
  for (int j = 0; j < 49; ++j)
    a7 = fmaf(WRAW(34 + j), c7[(j / 7 - 3) * PW_ + (j % 7 - 3)], a7);
#undef WRAW
  const float sc = 1.f / 65536.f;
  a3 *= sc; a5 *= sc; a7 *= sc;

  if (store_h) {
    out3[(size_t)b * bso + pc] = a3;
    out5[(size_t)b * bso + pc] = a5;
    out7[(size_t)b * bso + pc] = a7;
  }
  if (combo) {
    const float* cf = conf + ((size_t)b * 3) * HW_ + q;
    combo[(size_t)b * HW_ + q] =
        cf[0] * a3 + cf[(size_t)HW_] * a5 + cf[(size_t)2 * HW_] * a7;
  }
}

// ---------------------------------------------------------------------------
// K4: final conv + softmax + dot. ct-fout logits in wbuf ch 83..85; hn taps
// from padded field; mid/fin taps bounds-checked.
// ---------------------------------------------------------------------------
__global__ __launch_bounds__(256, 2) void k_final(
    const float* __restrict__ wbuf, const float* __restrict__ hnp,
    const float* __restrict__ mid, const float* __restrict__ fin,
    const float* __restrict__ prm, float* __restrict__ out)
{
  const float* ctw = prm + OCT;
  const int p = blockIdx.x * 256 + threadIdx.x;
  const int b = p / HW_, q = p - b * HW_;
  const int y = q / W_, x = q - y * W_;
  const size_t bo = (size_t)b * HW_;

  const float* lg = wbuf + ((size_t)b * WCH + 83) * HW_ + q;
  float l0 = prm[OCTB + 0] + lg[0];
  float l1 = prm[OCTB + 1] + lg[(size_t)HW_];
  float l2 = prm[OCTB + 2] + lg[(size_t)2 * HW_];

  const float* hc = hnp + (size_t)b * PHW_ + (size_t)(y + 3) * PW_ + (x + 3);
#pragma unroll
  for (int j = 0; j < 9; ++j) {
    float v = hc[(j / 3 - 1) * PW_ + (j % 3 - 1)];
    l0 = fmaf(v, ctw[(0 * 67 + 64) * 9 + j], l0);
    l1 = fmaf(v, ctw[(1 * 67 + 64) * 9 + j], l1);
    l2 = fmaf(v, ctw[(2 * 67 + 64) * 9 + j], l2);
  }
#pragma unroll
  for (int c = 1; c < 3; ++c) {
    const int icg = 64 + c;
    const float* src = (c == 1) ? mid : fin;
#pragma unroll
    for (int j = 0; j < 9; ++j) {
      int gy = y + j / 3 - 1, gx = x + j % 3 - 1;
      float v = 0.f;
      if ((unsigned)gy < H_ && (unsigned)gx < W_)
        v = src[bo + (size_t)gy * W_ + gx];
      l0 = fmaf(v, ctw[(0 * 67 + icg) * 9 + j], l0);
      l1 = fmaf(v, ctw[(1 * 67 + icg) * 9 + j], l1);
      l2 = fmaf(v, ctw[(2 * 67 + icg) * 9 + j], l2);
    }
  }
  float m = fmaxf(l0, fmaxf(l1, l2));
  float e0 = expf(l0 - m), e1 = expf(l1 - m), e2 = expf(l2 - m);
  float inv = 1.f / (e0 + e1 + e2);
  float h0c = hc[0];
  float r = (e0 * h0c + e1 * mid[bo + q] + e2 * fin[bo + q]) * inv;
  out[bo + q] = r;
}

// ---------------------------------------------------------------------------
// Host launch
// ---------------------------------------------------------------------------
extern "C" void kernel_launch(void* const* d_in, const int* in_sizes, int n_in,
                              void* d_out, int out_size, void* d_ws, size_t ws_size,
                              hipStream_t stream)
{
  static const int EXP[19] = {20971520, 327680, 327680, 4608, 8, 8, 13824, 24, 24,
                              27648, 48, 48, 1728, 3, 1809, 3, 1, 1, 1};
  const void* P[19];
  bool match = (n_in >= 19);
  for (int i = 0; i < 19 && match; ++i) if (in_sizes[i] != EXP[i]) match = false;
  if (match) {
    for (int i = 0; i < 19; ++i) P[i] = d_in[i];
  } else {
    bool used[64] = {false};
    for (int t = 0; t < 19; ++t) {
      P[t] = d_in[t < n_in ? t : 0];
      for (int i = 0; i < n_in && i < 64; ++i)
        if (!used[i] && in_sizes[i] == EXP[t]) { P[t] = d_in[i]; used[i] = true; break; }
    }
  }
  const void* fout = P[0];
  const void* hn   = P[1];
  float* out = (float*)d_out;

  // ws layout (floats):
  // [0,32) flags | [32,352) stat | [352,50138) prm | big @50176
  // big: wbuf 86*BHW | conf 3*BHW | Aset 12*PHW | hnp 4*PHW | midb | finb | xw
  // Total = 92*BHW + 16*PHW + 50176 floats = 126.3 MB  (ws verified >= 127.3)
  // After k_wt: weights live in wbuf ch 42..82 (+xw); ch 0..41 dead ->
  // B ping-pong fields alias wbuf ch 0..3.2 per batch (zeroed after k_wt).
  float* ws    = (float*)d_ws;
  int*   flags = (int*)ws;
  float* stat  = ws + 32;
  float* prm   = ws + 352;
  float* big   = ws + 50176;
  float* wbuf  = big;                              // 86*BHW
  float* conf  = wbuf + (size_t)WCH * BHW_;        // 3*BHW
  float* Abase = conf + (size_t)3 * BHW_;          // 12*PHW
  float* hnp   = Abase + (size_t)12 * PHW_;        // 4*PHW
  float* midb  = hnp + (size_t)4 * PHW_;           // BHW
  float* finb  = midb + (size_t)BHW_;              // BHW
  float* xw    = finb + (size_t)BHW_;              // BHW (pair 41)
  // apack (110592 u16) aliases midb (dead before it==2 writes midb).
  u16*   apack = (u16*)midb;

  // A-set field pointers (batch stride PHW_)
  float* a3f = Abase;
  float* a5f = Abase + (size_t)4 * PHW_;
  float* a7f = Abase + (size_t)8 * PHW_;
  // B-set field pointers alias wbuf ch 0.. (batch stride WCH*HW_)
  float* b3f = wbuf;
  float* b5f = wbuf + (size_t)PHW_;
  float* b7f = wbuf + (size_t)2 * PHW_;

  (void)hipMemsetAsync(stat, 0, 160 * sizeof(float), stream);
  (void)hipMemsetAsync(Abase, 0, (size_t)16 * PHW_ * sizeof(float), stream);

  k_detect<<<18, 512, 0, stream>>>(
      P[0], P[1], P[3], P[4], P[5], P[6], P[7], P[8],
      P[9], P[10], P[11], P[12], P[13], P[14], P[15],
      P[16], P[17], P[18], flags);

  k_cvt<<<(PRM_TOT + 255) / 256, 256, 0, stream>>>(
      P[3], P[6], P[9], P[12], P[14],
      P[4], P[5], P[7], P[8], P[10], P[11],
      P[13], P[15], P[16], P[17], P[18], prm, flags);

  k_padhn<<<1280, 256, 0, stream>>>(hn, hnp, flags);
  k_pack<<<432, 256, 0, stream>>>(prm, apack);
  k_conv_mfma<<<dim3(5, 64, 4), 256, 0, stream>>>(fout, apack, wbuf, flags);
  k_stats<<<dim3(32, 80), 256, 0, stream>>>(wbuf, stat);
  k_bn_finalize<<<1, 128, 0, stream>>>(stat);

  // it 0: fused weight-gen + first prop step -> A fields
  k_prop0<<<1280, 256, 0, stream>>>(
      wbuf, conf, hnp, a3f, a5f, a7f, prm, stat);

  // transpose weights pixel-major (ch 0..41 -> ch 43..82 + ch 42 + xw)
  k_wt<<<1280, 256, 0, stream>>>(wbuf, xw);

  // Zero B regions (wbuf ch 0.. dead only after k_wt's reads).
  for (int b = 0; b < 4; ++b)
    (void)hipMemsetAsync(wbuf + (size_t)b * WCH * HW_, 0,
                         (size_t)3 * PHW_ * sizeof(float), stream);

  const size_t bsA = PHW_;
  const size_t bsB = (size_t)WCH * HW_;
  // it1: A -> B
  k_prop_q<<<1280, 256, 0, stream>>>(wbuf, xw, conf, a3f, a5f, a7f, bsA,
                                     b3f, b5f, b7f, bsB, nullptr, 1);
  // it2: B -> A, combo=midb
  k_prop_q<<<1280, 256, 0, stream>>>(wbuf, xw, conf, b3f, b5f, b7f, bsB,
                                     a3f, a5f, a7f, bsA, midb, 1);
  // it3: A -> B
  k_prop_q<<<1280, 256, 0, stream>>>(wbuf, xw, conf, a3f, a5f, a7f, bsA,
                                     b3f, b5f, b7f, bsB, nullptr, 1);
  // it4: B -> A
  k_prop_q<<<1280, 256, 0, stream>>>(wbuf, xw, conf, b3f, b5f, b7f, bsB,
                                     a3f, a5f, a7f, bsA, nullptr, 1);
  // it5: A -> (combo only)
  k_prop_q<<<1280, 256, 0, stream>>>(wbuf, xw, conf, a3f, a5f, a7f, bsA,
                                     b3f, b5f, b7f, bsB, finb, 0);

  k_final<<<1280, 256, 0, stream>>>(wbuf, hnp, midb, finb, prm, out);
}

// Round 14
// 421.143 us; speedup vs baseline: 1.1372x; 1.1372x over previous
//
#include <hip/hip_runtime.h>
#include <hip/hip_bf16.h>
#include <math.h>

#define W_    320
#define H_    256
#define HW_   81920      // H_*W_
#define BHW_  327680     // 4*HW_
#define PRM_TOT 49786
#define WCH   86         // wbuf channels/batch: 83 gen-kernel + 3 ct-logit
#define PW_   326        // padded field width  (W + 2*3)
#define PH_   262        // padded field height (H + 2*3)
#define PHW_  85412      // PW_*PH_

// prm layout offsets (floats)
#define OW3  0
#define OW5  4608
#define OW7  18432
#define OCK  46080
#define OCT  47808
#define OG3  49617
#define OB3  49625
#define OG5  49633
#define OB5  49657
#define OG7  49681
#define OB7  49729
#define OCKB 49777
#define OCTB 49780
#define OSIG 49783

typedef unsigned short u16;
typedef __attribute__((ext_vector_type(8))) short short8;   // 8 bf16 (4 VGPRs)
typedef __attribute__((ext_vector_type(4))) float f32x4;    // MFMA C/D

__device__ __forceinline__ float dload(const void* p, size_t i, int isbf) {
  return isbf ? __bfloat162float(((const __hip_bfloat16*)p)[i])
              : ((const float*)p)[i];
}

__device__ __forceinline__ u16 f32_bf16_rne(float f) {
  union { float f; unsigned u; } v; v.f = f;
  unsigned r = v.u + 0x7FFFu + ((v.u >> 16) & 1u);
  return (u16)(r >> 16);
}
__device__ __forceinline__ float bf16_f32(u16 h) {
  union { unsigned u; float f; } v; v.u = ((unsigned)h) << 16;
  return v.f;
}

// Weight quantization: weights provably in [0,1]; u16 fixed point, 2^-16.
__device__ __forceinline__ unsigned wquant(float w) {
  int v = (int)(w * 65536.f + 0.5f);
  return (unsigned)(v > 65535 ? 65535 : (v < 0 ? 0 : v));
}

// ---------------------------------------------------------------------------
// Per-tensor dtype detector (kept for robustness; observed: all f32).
// ---------------------------------------------------------------------------
__global__ __launch_bounds__(512) void k_detect(
    const void* t0, const void* t1, const void* t2, const void* t3,
    const void* t4, const void* t5, const void* t6, const void* t7,
    const void* t8, const void* t9, const void* t10, const void* t11,
    const void* t12, const void* t13, const void* t14, const void* t15,
    const void* t16, const void* t17, int* __restrict__ flags)
{
  __shared__ int c_other, c_zeven, c_zodd, c_m;
  const void* ptrs[18] = {t0,t1,t2,t3,t4,t5,t6,t7,t8,t9,
                          t10,t11,t12,t13,t14,t15,t16,t17};
  const int ns[18] = {20971520, 327680, 4608, 8, 8, 13824, 24, 24,
                      27648, 48, 48, 1728, 3, 1809, 3, 1, 1, 1};
  const int tensor = blockIdx.x;
  const int n = ns[tensor];
  const unsigned short* u = (const unsigned short*)ptrs[tensor];
  if (threadIdx.x == 0) { c_other = 0; c_zeven = 0; c_zodd = 0; c_m = 0; }
  __syncthreads();
  {
    int k = threadIdx.x >> 1;
    long long pos = (long long)k * n / 256;
    int j = ((int)pos & ~1) + (threadIdx.x & 1);
    if (j < n) {
      unsigned short v = u[j];
      int e = (v >> 7) & 0xFF;
      atomicAdd(&c_m, 1);
      if (v != 0 && (e < 90 || e > 150)) atomicAdd(&c_other, 1);
      if (v == 0) {
        if (j & 1) atomicAdd(&c_zodd, 1); else atomicAdd(&c_zeven, 1);
      }
    }
  }
  __syncthreads();
  if (threadIdx.x == 0) {
    int isf32;
    if (n == 1) isf32 = (u[0] == 0);
    else        isf32 = (4 * c_other >= c_m) ||
                        (2 * (c_zeven - c_zodd) >= c_m);
    flags[tensor] = isf32 ? 0 : 1;
  }
}

// ---------------------------------------------------------------------------
// K0: convert params to f32 staging `prm` (per-tensor dtype).
// ---------------------------------------------------------------------------
__global__ __launch_bounds__(256) void k_cvt(
    const void* w3c, const void* w5c, const void* w7c, const void* ckw, const void* ctw,
    const void* g3, const void* b3, const void* g5, const void* b5,
    const void* g7, const void* b7, const void* ckb, const void* ctb,
    const void* s3, const void* s5, const void* s7,
    float* __restrict__ prm, const int* __restrict__ flags)
{
  int j = blockIdx.x * 256 + threadIdx.x;
  if (j >= PRM_TOT) return;
  const void* src; int off; int fid;
  if      (j < OW5)    { src = w3c; off = OW3;  fid = 2; }
  else if (j < OW7)    { src = w5c; off = OW5;  fid = 5; }
  else if (j < OCK)    { src = w7c; off = OW7;  fid = 8; }
  else if (j < OCT)    { src = ckw; off = OCK;  fid = 11; }
  else if (j < OG3)    { src = ctw; off = OCT;  fid = 13; }
  else if (j < OB3)    { src = g3;  off = OG3;  fid = 3; }
  else if (j < OG5)    { src = b3;  off = OB3;  fid = 4; }
  else if (j < OB5)    { src = g5;  off = OG5;  fid = 6; }
  else if (j < OG7)    { src = b5;  off = OB5;  fid = 7; }
  else if (j < OB7)    { src = g7;  off = OG7;  fid = 9; }
  else if (j < OCKB)   { src = b7;  off = OB7;  fid = 10; }
  else if (j < OCTB)   { src = ckb; off = OCKB; fid = 12; }
  else if (j < OSIG)   { src = ctb; off = OCTB; fid = 14; }
  else if (j < OSIG+1) { src = s3;  off = OSIG;   fid = 15; }
  else if (j < OSIG+2) { src = s5;  off = OSIG+1; fid = 16; }
  else                 { src = s7;  off = OSIG+2; fid = 17; }
  prm[j] = dload(src, j - off, flags[fid]);
}

// ---------------------------------------------------------------------------
// K0c: stage hn into a padded f32 field (3-px zero halo, dtype-converted).
// ---------------------------------------------------------------------------
__global__ __launch_bounds__(256) void k_padhn(
    const void* __restrict__ rawhn, float* __restrict__ hnp,
    const int* __restrict__ flags)
{
  const int isbf = flags[1];
  const int p = blockIdx.x * 256 + threadIdx.x;
  const int b = p / HW_, q = p - b * HW_;
  const int y = q / W_, x = q - y * W_;
  hnp[(size_t)b * PHW_ + (size_t)(y + 3) * PW_ + (x + 3)] =
      dload(rawhn, (size_t)b * HW_ + q, isbf);
}

// ---------------------------------------------------------------------------
// K0b: pack conv weights into MFMA A-fragment order, split bf16 hi/lo.
// ---------------------------------------------------------------------------
__global__ __launch_bounds__(256) void k_pack(
    const float* __restrict__ prm, u16* __restrict__ apack)
{
  int idx = blockIdx.x * 256 + threadIdx.x;   // grid exactly 110592
  int e = idx & 7;
  int lane = (idx >> 3) & 63;
  int t = idx >> 9;
  int mt = t % 6; t /= 6;
  int chunk = t & 1; t >>= 1;
  int tap = t % 9;
  int hilo = t / 9;
  int oc = mt * 16 + (lane & 15);
  int ic = chunk * 32 + (lane >> 4) * 8 + e;
  float w = 0.f;
  if (oc < 83)      w = prm[(size_t)oc * 576 + (size_t)ic * 9 + tap];
  else if (oc < 86) w = prm[OCT + (size_t)((oc - 83) * 67 + ic) * 9 + tap];
  u16 h = f32_bf16_rne(w);
  u16 outv = (hilo == 0) ? h : f32_bf16_rne(w - bf16_f32(h));
  apack[idx] = outv;
}

// ---------------------------------------------------------------------------
// Staging: fout tile [6 rows][66 px][32 ic-chunk] -> LDS bf16 hi + lo.
// ---------------------------------------------------------------------------
template<int ISBF>
__device__ __forceinline__ void stage_chunk(
    const void* __restrict__ fout, int b, int y0, int x0, int chunk,
    u16* Bhi, u16* Blo)
{
  const int g = threadIdx.x & 3;        // ic8 group within chunk
  const int cell0 = threadIdx.x >> 2;   // (row,px) cell, 0..63
  const size_t fb = (size_t)b * 64 * HW_ + (size_t)(chunk * 32 + g * 8) * HW_;
#pragma unroll
  for (int it = 0; it < 7; ++it) {
    int cell = cell0 + it * 64;
    if (cell < 396) {
      int row = cell / 66;
      int px = cell - row * 66;
      int gy = y0 - 1 + row, gx = x0 - 1 + px;
      bool ok = ((unsigned)gy < H_) && ((unsigned)gx < W_);
      size_t base = fb + (size_t)gy * W_ + gx;
      short8 hs = {0,0,0,0,0,0,0,0};
      short8 ls = {0,0,0,0,0,0,0,0};
#pragma unroll
      for (int i = 0; i < 8; ++i) {
        float v = ok ? dload(fout, base + (size_t)i * HW_, ISBF) : 0.f;
        union { float f; unsigned u; } uv; uv.f = v;
        u16 h = (u16)(uv.u >> 16);               // truncate: hi
        float resid = v - bf16_f32(h);           // exact residual
        hs[i] = (short)h;
        ls[i] = (short)f32_bf16_rne(resid);
      }
      int off = ((row * 66 + px) * 32 + g * 8) * 2;
      off ^= (px & 7) << 4;
      *(short8*)((char*)Bhi + off) = hs;
      *(short8*)((char*)Blo + off) = ls;
    }
  }
}

// ---------------------------------------------------------------------------
// K1: 3x3 conv 64->86 as implicit GEMM on MFMA (split-bf16, 3-term).
// FROZEN (round-11 verified clean): 256 thr = 4 waves, 6 mtiles/wave,
// (256,2) = 256-reg budget (128 arch + 96 acc fits), C-store-only epilogue.
// ---------------------------------------------------------------------------
__global__ __launch_bounds__(256, 2) void k_conv_mfma(
    const void* __restrict__ fout, const u16* __restrict__ apack,
    float* __restrict__ wbuf, const int* __restrict__ flags)
{
  __shared__ __align__(16) u16 Bhi[6 * 66 * 32];
  __shared__ __align__(16) u16 Blo[6 * 66 * 32];
  const int isbf = flags[0];
  const int x0 = blockIdx.x * 64;
  const int y0 = blockIdx.y * 4;
  const int b  = blockIdx.z;
  const int lane = threadIdx.x & 63;
  const int wv   = threadIdx.x >> 6;    // 0..3 = row within tile

  const f32x4 zero = {0.f, 0.f, 0.f, 0.f};
  f32x4 acc[6][4];
#pragma unroll
  for (int mt = 0; mt < 6; ++mt)
#pragma unroll
    for (int nt = 0; nt < 4; ++nt)
      acc[mt][nt] = zero;

  for (int chunk = 0; chunk < 2; ++chunk) {
    if (chunk) __syncthreads();
    if (isbf) stage_chunk<1>(fout, b, y0, x0, chunk, Bhi, Blo);
    else      stage_chunk<0>(fout, b, y0, x0, chunk, Bhi, Blo);
    __syncthreads();

#pragma unroll
    for (int tap = 0; tap < 9; ++tap) {
      const int dy = tap / 3, dx = tap - dy * 3;
      const int row = wv + dy;
      short8 bh[4], bl[4];
#pragma unroll
      for (int nt = 0; nt < 4; ++nt) {
        int px = nt * 16 + (lane & 15) + dx;
        int off = ((row * 66 + px) * 32 + (lane >> 4) * 8) * 2;
        off ^= (px & 7) << 4;
        bh[nt] = *(const short8*)((const char*)Bhi + off);
        bl[nt] = *(const short8*)((const char*)Blo + off);
      }
      const u16* abase = apack + (size_t)(tap * 2 + chunk) * 3072 + (size_t)lane * 8;
#pragma unroll
      for (int mt = 0; mt < 6; ++mt) {
        short8 ah = *(const short8*)(abase + (size_t)mt * 512);
        short8 al = *(const short8*)(abase + (size_t)mt * 512 + 55296);
#pragma unroll
        for (int nt = 0; nt < 4; ++nt) {
          acc[mt][nt] = __builtin_amdgcn_mfma_f32_16x16x32_bf16(ah, bh[nt], acc[mt][nt], 0, 0, 0);
          acc[mt][nt] = __builtin_amdgcn_mfma_f32_16x16x32_bf16(ah, bl[nt], acc[mt][nt], 0, 0, 0);
          acc[mt][nt] = __builtin_amdgcn_mfma_f32_16x16x32_bf16(al, bh[nt], acc[mt][nt], 0, 0, 0);
        }
      }
    }
  }

  // Epilogue: C/D layout col=lane&15 (px), row=(lane>>4)*4+reg (oc). [m89]
  const int ocr = (lane >> 4) * 4;
  float* wb = wbuf + (size_t)b * WCH * HW_
            + (size_t)(y0 + wv) * W_ + x0 + (lane & 15);
#pragma unroll
  for (int mt = 0; mt < 6; ++mt) {
#pragma unroll
    for (int nt = 0; nt < 4; ++nt) {
#pragma unroll
      for (int r = 0; r < 4; ++r) {
        int oc = mt * 16 + ocr + r;
        if (oc < 86)
          wb[(size_t)oc * HW_ + nt * 16] = acc[mt][nt][r];
      }
    }
  }
}

// ---------------------------------------------------------------------------
// K1s: BN statistics over wbuf channels 0..79 (WCH stride), float4 loads
// (coalesced along q; 4x fewer load instructions on the 105 MB stream).
// ---------------------------------------------------------------------------
__global__ __launch_bounds__(256) void k_stats(
    const float* __restrict__ wbuf, float* __restrict__ stat)
{
  const int ch = blockIdx.y;
  const int HW4 = HW_ / 4;
  float s = 0.f, qq = 0.f;
  for (int idx = blockIdx.x * 256 + threadIdx.x; idx < BHW_ / 4;
       idx += gridDim.x * 256) {
    int b = idx / HW4, r = idx - b * HW4;
    float4 v = *(const float4*)(wbuf + ((size_t)(b * WCH + ch)) * HW_ +
                                (size_t)r * 4);
    s  += v.x + v.y + v.z + v.w;
    qq += v.x * v.x + v.y * v.y + v.z * v.z + v.w * v.w;
  }
#pragma unroll
  for (int m = 1; m < 64; m <<= 1) {
    s += __shfl_xor(s, m, 64);
    qq += __shfl_xor(qq, m, 64);
  }
  __shared__ float rs[4], rq[4];
  const int lane = threadIdx.x & 63, wv = threadIdx.x >> 6;
  if (lane == 0) { rs[wv] = s; rq[wv] = qq; }
  __syncthreads();
  if (threadIdx.x == 0) {
    float ts = rs[0] + rs[1] + rs[2] + rs[3];
    float tq = rq[0] + rq[1] + rq[2] + rq[3];
    atomicAdd(&stat[ch], ts);
    atomicAdd(&stat[80 + ch], tq);
  }
}

// ---------------------------------------------------------------------------
// K1b: finalize BN mean / invstd
// ---------------------------------------------------------------------------
__global__ void k_bn_finalize(float* __restrict__ stat)
{
  int ch = threadIdx.x;
  if (ch < 80) {
    const float n = 1.f / (float)BHW_;
    float m = stat[ch] * n;
    float var = stat[80 + ch] * n - m * m;
    stat[160 + ch] = m;
    stat[240 + ch] = rsqrtf(var + 1e-5f);
  }
}

// ---------------------------------------------------------------------------
// K2: fused weight-gen + prop iteration 0. Reads padded hn (unconditional
// immediate-offset taps); writes h outputs into padded A fields (batch
// stride PHW_). Quantize-pack into wbuf slots 0..41 (channel-major —
// round-13's pixel-major transpose destroyed coalescing, −45 µs; reverted).
// ---------------------------------------------------------------------------
__global__ __launch_bounds__(256, 2) void k_prop0(
    float* __restrict__ wbuf, float* __restrict__ conf,
    const float* __restrict__ hnp,
    float* __restrict__ h3o, float* __restrict__ h5o, float* __restrict__ h7o,
    const float* __restrict__ prm, const float* __restrict__ stat)
{
  const int p = blockIdx.x * 256 + threadIdx.x;
  const int b = p / HW_, q = p - b * HW_;
  const int y = q / W_, x = q - y * W_;
  float* base = wbuf + ((size_t)b * WCH) * HW_ + q;
  const float* mean = stat + 160;
  const float* istd = stat + 240;
  const size_t pc = (size_t)b * PHW_ + (size_t)(y + 3) * PW_ + (x + 3);
  const float* hc = hnp + pc;

  // ---- conf softmax (raw ck channels 80..82) ----
  {
    float c0 = base[(size_t)80 * HW_] + prm[OCKB + 0];
    float c1 = base[(size_t)81 * HW_] + prm[OCKB + 1];
    float c2 = base[(size_t)82 * HW_] + prm[OCKB + 2];
    float m = fmaxf(c0, fmaxf(c1, c2));
    float e0 = expf(c0 - m), e1 = expf(c1 - m), e2 = expf(c2 - m);
    float inv = 1.f / (e0 + e1 + e2);
    float* cf = conf + ((size_t)b * 3) * HW_ + q;
    cf[0] = e0 * inv;
    cf[(size_t)HW_] = e1 * inv;
    cf[(size_t)2 * HW_] = e2 * inv;
  }

  float a3, a5, a7;
  unsigned carry;   // low half of pair 4 (kernel channel 8)

  // ---- pk=3 ----
  {
    float cvv[8]; float s = 0.f;
#pragma unroll
    for (int i = 0; i < 8; ++i) {
      float v = base[(size_t)i * HW_];
      v = fmaxf(0.f, (v - mean[i]) * istd[i] * prm[OG3 + i] + prm[OB3 + i]);
      cvv[i] = v; s += v;
    }
    float inv = 1.f / (s + 1e-6f);
    float ctr = 1.f - s * inv;
    float sg = prm[OSIG + 0];
    float a = 0.5f / (sg * sg);
    float e1 = expf(-a);
    float g1[3] = {e1, 1.f, e1};
    float tot = 0.f;
#pragma unroll
    for (int j = 0; j < 9; ++j) {
      float w = (j == 4) ? ctr : cvv[j < 4 ? j : j - 1] * inv;
      w *= g1[j / 3] * g1[j % 3];
      if (j == 4) ctr = w; else cvv[j < 4 ? j : j - 1] = w;
      tot += w;
    }
    float rr = 1.f / fmaxf(tot, 1e-7f);
    auto wk = [&](int c) -> float {
      return ((c == 4) ? ctr : cvv[c < 4 ? c : c - 1]) * rr;
    };
    a3 = 0.f;
#pragma unroll
    for (int j = 0; j < 9; ++j)
      a3 = fmaf(wk(j), hc[(j / 3 - 1) * PW_ + (j % 3 - 1)], a3);
#pragma unroll
    for (int pr = 0; pr < 4; ++pr)
      base[(size_t)pr * HW_] =
          __uint_as_float(wquant(wk(2 * pr)) | (wquant(wk(2 * pr + 1)) << 16));
    carry = wquant(wk(8));
  }

  // ---- pk=5 ----
  {
    float cvv[24]; float s = 0.f;
#pragma unroll
    for (int i = 0; i < 24; ++i) {
      float v = base[(size_t)(8 + i) * HW_];
      v = fmaxf(0.f, (v - mean[8 + i]) * istd[8 + i] * prm[OG5 + i] + prm[OB5 + i]);
      cvv[i] = v; s += v;
    }
    float inv = 1.f / (s + 1e-6f);
    float ctr = 1.f - s * inv;
    float sg = prm[OSIG + 1];
    float a = 0.5f / (sg * sg);
    float ea = expf(-a), eb = expf(-0.25f * a);
    float g1[5] = {ea, eb, 1.f, eb, ea};
    float tot = 0.f;
#pragma unroll
    for (int j = 0; j < 25; ++j) {
      float w = (j == 12) ? ctr : cvv[j < 12 ? j : j - 1] * inv;
      w *= g1[j / 5] * g1[j % 5];
      if (j == 12) ctr = w; else cvv[j < 12 ? j : j - 1] = w;
      tot += w;
    }
    float rr = 1.f / fmaxf(tot, 1e-7f);
    auto wk = [&](int j) -> float {
      return ((j == 12) ? ctr : cvv[j < 12 ? j : j - 1]) * rr;
    };
    a5 = 0.f;
#pragma unroll
    for (int j = 0; j < 25; ++j)
      a5 = fmaf(wk(j), hc[(j / 5 - 2) * PW_ + (j % 5 - 2)], a5);
    base[(size_t)4 * HW_] = __uint_as_float(carry | (wquant(wk(0)) << 16));
#pragma unroll
    for (int m = 0; m < 12; ++m)
      base[(size_t)(5 + m) * HW_] =
          __uint_as_float(wquant(wk(1 + 2 * m)) | (wquant(wk(2 + 2 * m)) << 16));
  }

  // ---- pk=7 ----
  {
    float cvv[48]; float s = 0.f;
#pragma unroll
    for (int i = 0; i < 48; ++i) {
      float v = base[(size_t)(32 + i) * HW_];
      v = fmaxf(0.f, (v - mean[32 + i]) * istd[32 + i] * prm[OG7 + i] + prm[OB7 + i]);
      cvv[i] = v; s += v;
    }
    float inv = 1.f / (s + 1e-6f);
    float ctr = 1.f - s * inv;
    float sg = prm[OSIG + 2];
    float a = 0.5f / (sg * sg);
    float ea = expf(-a), eb = expf(-(4.f / 9.f) * a), ec = expf(-(1.f / 9.f) * a);
    float g1[7] = {ea, eb, ec, 1.f, ec, eb, ea};
    float tot = 0.f;
#pragma unroll
    for (int j = 0; j < 49; ++j) {
      float w = (j == 24) ? ctr : cvv[j < 24 ? j : j - 1] * inv;
      w *= g1[j / 7] * g1[j % 7];
      if (j == 24) ctr = w; else cvv[j < 24 ? j : j - 1] = w;
      tot += w;
    }
    float rr = 1.f / fmaxf(tot, 1e-7f);
    auto wk = [&](int j) -> float {
      return ((j == 24) ? ctr : cvv[j < 24 ? j : j - 1]) * rr;
    };
    a7 = 0.f;
#pragma unroll
    for (int j = 0; j < 49; ++j)
      a7 = fmaf(wk(j), hc[(j / 7 - 3) * PW_ + (j % 7 - 3)], a7);
#pragma unroll
    for (int m = 0; m < 24; ++m)
      base[(size_t)(17 + m) * HW_] =
          __uint_as_float(wquant(wk(2 * m)) | (wquant(wk(2 * m + 1)) << 16));
    base[(size_t)41 * HW_] = __uint_as_float(wquant(wk(48)));
  }

  h3o[pc] = a3;
  h5o[pc] = a5;
  h7o[pc] = a7;
}

// ---------------------------------------------------------------------------
// K3: propagation iterations 1..5, padded fields, channel-major weights
// (42 perfectly-coalesced dword loads — proven best layout, round 12/13 A/B).
// Every tap is an unconditional load at a compile-time immediate offset.
// Raw-u16 accumulate, single 2^-16 scale (exact).
// ---------------------------------------------------------------------------
__global__ __launch_bounds__(256) void k_prop_q(
    const float* __restrict__ wbuf, const float* __restrict__ conf,
    const float* __restrict__ in3, const float* __restrict__ in5,
    const float* __restrict__ in7, size_t bsi,
    float* __restrict__ out3, float* __restrict__ out5,
    float* __restrict__ out7, size_t bso,
    float* __restrict__ combo, int store_h)
{
  const int p = blockIdx.x * 256 + threadIdx.x;
  const int b = p / HW_, q = p - b * HW_;
  const int y = q / W_, x = q - y * W_;
  const float* base = wbuf + ((size_t)b * WCH) * HW_ + q;

  unsigned pk[42];
#pragma unroll
  for (int pr = 0; pr < 42; ++pr)
    pk[pr] = __float_as_uint(base[(size_t)pr * HW_]);
#define WRAW(CH) ((float)((pk[(CH) >> 1] >> (((CH) & 1) * 16)) & 0xffffu))

  const size_t pc = (size_t)(y + 3) * PW_ + (x + 3);
  const float* c3 = in3 + (size_t)b * bsi + pc;
  const float* c5 = in5 + (size_t)b * bsi + pc;
  const float* c7 = in7 + (size_t)b * bsi + pc;

  float a3 = 0.f, a5 = 0.f, a7 = 0.f;
#pragma unroll
  for (int j = 0; j < 9; ++j)
    a3 = fmaf(WRAW(j), c3[(j / 3 - 1) * PW_ + (j % 3 - 1)], a3);
#pragma unroll
  for (int j = 0; j < 25; ++j)
    a5 = fmaf(WRAW(9 + j), c5[(j / 5 - 2) * PW_ + (j % 5 - 2)], a5);
#pragma unroll
  for (int j = 0; j < 49; ++j)
    a7 = fmaf(WRAW(34 + j), c7[(j / 7 - 3) * PW_ + (j % 7 - 3)], a7);
#undef WRAW
  const float sc = 1.f / 65536.f;
  a3 *= sc; a5 *= sc; a7 *= sc;

  if (store_h) {
    out3[(size_t)b * bso + pc] = a3;
    out5[(size_t)b * bso + pc] = a5;
    out7[(size_t)b * bso + pc] = a7;
  }
  if (combo) {
    const float* cf = conf + ((size_t)b * 3) * HW_ + q;
    combo[(size_t)b * HW_ + q] =
        cf[0] * a3 + cf[(size_t)HW_] * a5 + cf[(size_t)2 * HW_] * a7;
  }
}

// ---------------------------------------------------------------------------
// K4: final conv + softmax + dot. ct-fout logits in wbuf ch 83..85; hn taps
// from padded field; mid/fin taps bounds-checked.
// ---------------------------------------------------------------------------
__global__ __launch_bounds__(256, 2) void k_final(
    const float* __restrict__ wbuf, const float* __restrict__ hnp,
    const float* __restrict__ mid, const float* __restrict__ fin,
    const float* __restrict__ prm, float* __restrict__ out)
{
  const float* ctw = prm + OCT;
  const int p = blockIdx.x * 256 + threadIdx.x;
  const int b = p / HW_, q = p - b * HW_;
  const int y = q / W_, x = q - y * W_;
  const size_t bo = (size_t)b * HW_;

  const float* lg = wbuf + ((size_t)b * WCH + 83) * HW_ + q;
  float l0 = prm[OCTB + 0] + lg[0];
  float l1 = prm[OCTB + 1] + lg[(size_t)HW_];
  float l2 = prm[OCTB + 2] + lg[(size_t)2 * HW_];

  const float* hc = hnp + (size_t)b * PHW_ + (size_t)(y + 3) * PW_ + (x + 3);
#pragma unroll
  for (int j = 0; j < 9; ++j) {
    float v = hc[(j / 3 - 1) * PW_ + (j % 3 - 1)];
    l0 = fmaf(v, ctw[(0 * 67 + 64) * 9 + j], l0);
    l1 = fmaf(v, ctw[(1 * 67 + 64) * 9 + j], l1);
    l2 = fmaf(v, ctw[(2 * 67 + 64) * 9 + j], l2);
  }
#pragma unroll
  for (int c = 1; c < 3; ++c) {
    const int icg = 64 + c;
    const float* src = (c == 1) ? mid : fin;
#pragma unroll
    for (int j = 0; j < 9; ++j) {
      int gy = y + j / 3 - 1, gx = x + j % 3 - 1;
      float v = 0.f;
      if ((unsigned)gy < H_ && (unsigned)gx < W_)
        v = src[bo + (size_t)gy * W_ + gx];
      l0 = fmaf(v, ctw[(0 * 67 + icg) * 9 + j], l0);
      l1 = fmaf(v, ctw[(1 * 67 + icg) * 9 + j], l1);
      l2 = fmaf(v, ctw[(2 * 67 + icg) * 9 + j], l2);
    }
  }
  float m = fmaxf(l0, fmaxf(l1, l2));
  float e0 = expf(l0 - m), e1 = expf(l1 - m), e2 = expf(l2 - m);
  float inv = 1.f / (e0 + e1 + e2);
  float h0c = hc[0];
  float r = (e0 * h0c + e1 * mid[bo + q] + e2 * fin[bo + q]) * inv;
  out[bo + q] = r;
}

// ---------------------------------------------------------------------------
// Host launch
// ---------------------------------------------------------------------------
extern "C" void kernel_launch(void* const* d_in, const int* in_sizes, int n_in,
                              void* d_out, int out_size, void* d_ws, size_t ws_size,
                              hipStream_t stream)
{
  static const int EXP[19] = {20971520, 327680, 327680, 4608, 8, 8, 13824, 24, 24,
                              27648, 48, 48, 1728, 3, 1809, 3, 1, 1, 1};
  const void* P[19];
  bool match = (n_in >= 19);
  for (int i = 0; i < 19 && match; ++i) if (in_sizes[i] != EXP[i]) match = false;
  if (match) {
    for (int i = 0; i < 19; ++i) P[i] = d_in[i];
  } else {
    bool used[64] = {false};
    for (int t = 0; t < 19; ++t) {
      P[t] = d_in[t < n_in ? t : 0];
      for (int i = 0; i < n_in && i < 64; ++i)
        if (!used[i] && in_sizes[i] == EXP[t]) { P[t] = d_in[i]; used[i] = true; break; }
    }
  }
  const void* fout = P[0];
  const void* hn   = P[1];
  float* out = (float*)d_out;

  // ws layout (floats), small buffers FIRST:
  // [0,32) flags | [32,352) stat | [352,50138) prm | big @50176
  // big: wbuf 86*BHW | conf 3*BHW | Aset 12*PHW | hnp 4*PHW | midb | finb
  // B ping-pong fields alias wbuf channels 42..45+ (dead after k_prop0;
  // zeroed AFTER prop0, written from it1).
  float* ws    = (float*)d_ws;
  int*   flags = (int*)ws;
  float* stat  = ws + 32;
  float* prm   = ws + 352;
  float* big   = ws + 50176;
  float* wbuf  = big;                              // 86*BHW
  float* conf  = wbuf + (size_t)WCH * BHW_;        // 3*BHW
  float* Abase = conf + (size_t)3 * BHW_;          // 12*PHW
  float* hnp   = Abase + (size_t)12 * PHW_;        // 4*PHW
  float* midb  = hnp + (size_t)4 * PHW_;           // BHW
  float* finb  = midb + (size_t)BHW_;              // BHW
  // apack (110592 u16) aliases midb (dead before it==2 writes midb).
  u16*   apack = (u16*)midb;

  // A-set field pointers (batch stride PHW_)
  float* a3f = Abase;
  float* a5f = Abase + (size_t)4 * PHW_;
  float* a7f = Abase + (size_t)8 * PHW_;
  // B-set field pointers alias wbuf ch 42.. (batch stride WCH*HW_)
  float* b3f = wbuf + (size_t)42 * HW_;
  float* b5f = b3f + (size_t)PHW_;
  float* b7f = b3f + (size_t)2 * PHW_;

  (void)hipMemsetAsync(stat, 0, 160 * sizeof(float), stream);
  (void)hipMemsetAsync(Abase, 0, (size_t)16 * PHW_ * sizeof(float), stream);

  k_detect<<<18, 512, 0, stream>>>(
      P[0], P[1], P[3], P[4], P[5], P[6], P[7], P[8],
      P[9], P[10], P[11], P[12], P[13], P[14], P[15],
      P[16], P[17], P[18], flags);

  k_cvt<<<(PRM_TOT + 255) / 256, 256, 0, stream>>>(
      P[3], P[6], P[9], P[12], P[14],
      P[4], P[5], P[7], P[8], P[10], P[11],
      P[13], P[15], P[16], P[17], P[18], prm, flags);

  k_padhn<<<1280, 256, 0, stream>>>(hn, hnp, flags);
  k_pack<<<432, 256, 0, stream>>>(prm, apack);
  k_conv_mfma<<<dim3(5, 64, 4), 256, 0, stream>>>(fout, apack, wbuf, flags);
  k_stats<<<dim3(32, 80), 256, 0, stream>>>(wbuf, stat);
  k_bn_finalize<<<1, 128, 0, stream>>>(stat);

  // it 0: fused weight-gen + first prop step -> A fields
  k_prop0<<<1280, 256, 0, stream>>>(
      wbuf, conf, hnp, a3f, a5f, a7f, prm, stat);

  // Zero B regions (wbuf ch 42.. are dead only after prop0's reads).
  for (int b = 0; b < 4; ++b)
    (void)hipMemsetAsync(wbuf + ((size_t)b * WCH + 42) * HW_, 0,
                         (size_t)3 * PHW_ * sizeof(float), stream);

  const size_t bsA = PHW_;
  const size_t bsB = (size_t)WCH * HW_;
  // it1: A -> B
  k_prop_q<<<1280, 256, 0, stream>>>(wbuf, conf, a3f, a5f, a7f, bsA,
                                     b3f, b5f, b7f, bsB, nullptr, 1);
  // it2: B -> A, combo=midb
  k_prop_q<<<1280, 256, 0, stream>>>(wbuf, conf, b3f, b5f, b7f, bsB,
                                     a3f, a5f, a7f, bsA, midb, 1);
  // it3: A -> B
  k_prop_q<<<1280, 256, 0, stream>>>(wbuf, conf, a3f, a5f, a7f, bsA,
                                     b3f, b5f, b7f, bsB, nullptr, 1);
  // it4: B -> A
  k_prop_q<<<1280, 256, 0, stream>>>(wbuf, conf, b3f, b5f, b7f, bsB,
                                     a3f, a5f, a7f, bsA, nullptr, 1);
  // it5: A -> (combo only)
  k_prop_q<<<1280, 256, 0, stream>>>(wbuf, conf, a3f, a5f, a7f, bsA,
                                     b3f, b5f, b7f, bsB, finb, 0);

  k_final<<<1280, 256, 0, stream>>>(wbuf, hnp, midb, finb, prm, out);
}